// Round 2
// baseline (1413.799 us; speedup 1.0000x reference)
//
#include <hip/hip_runtime.h>
#include <hip/hip_bf16.h>

// QLSTM: T=512, B=256, D=128, H=256, P=128, GAMMA=1
// Phase 1 (parallel): Sx[t*B+b, p] = sum_{d<D} (x[t,b,d]-proto[p,d])^2   (fp16 in d_ws, 32MB)
// Phase 2 (sequential over T, 1 WG per batch row):
//   Sh[p] = ||hx||^2 - 2 hx.ph[p] + ||ph[p]||^2 ; k = exp(-(Sx+Sh))
//   gates = act(k @ W^T + b) with fp16 weights held in VGPRs, v_dot2_f32_f16 MACs.

#define TT 512
#define BB 256
#define DD 128
#define HH 256
#define PP 128
#define DHH 384

typedef _Float16 h2 __attribute__((ext_vector_type(2)));

__device__ __forceinline__ float fdot2f(h2 a, h2 b, float c) {
#if __has_builtin(__builtin_amdgcn_fdot2)
  return __builtin_amdgcn_fdot2(a, b, c, false);
#else
  return c + (float)a.x * (float)b.x + (float)a.y * (float)b.y;
#endif
}

__device__ __forceinline__ float sigm_f(float x) {
  return 1.f / (1.f + __expf(-x));
}
__device__ __forceinline__ float tanh_f(float x) {
  return 1.f - 2.f / (1.f + __expf(2.f * x));
}

// ---------------- Phase 1: x-part of RBF distances ----------------
// grid 1024 x 256. Thread owns p = tid&127; halves of the block stripe rows.
__global__ __launch_bounds__(256) void sx_kernel(const float* __restrict__ x,
                                                 const float* __restrict__ proto,
                                                 _Float16* __restrict__ sx) {
  const int tid = threadIdx.x;
  const int p = tid & (PP - 1);
  const int half_ = tid >> 7;

  float px[DD];
#pragma unroll
  for (int d = 0; d < DD; d += 4) {
    const float4 v = *(const float4*)(proto + p * DHH + d);
    px[d] = v.x; px[d + 1] = v.y; px[d + 2] = v.z; px[d + 3] = v.w;
  }

  const int rowsPerWg = (TT * BB) / 1024;  // 128
  const int r0 = blockIdx.x * rowsPerWg;
  for (int r = r0 + half_; r < r0 + rowsPerWg; r += 2) {
    const float* xr = x + (size_t)r * DD;
    float acc = 0.f;
#pragma unroll
    for (int d = 0; d < DD; d += 4) {
      const float4 v = *(const float4*)(xr + d);  // wave-uniform address: broadcast
      float t0 = v.x - px[d];     acc = fmaf(t0, t0, acc);
      float t1 = v.y - px[d + 1]; acc = fmaf(t1, t1, acc);
      float t2 = v.z - px[d + 2]; acc = fmaf(t2, t2, acc);
      float t3 = v.w - px[d + 3]; acc = fmaf(t3, t3, acc);
    }
    sx[(size_t)r * PP + p] = (_Float16)acc;
  }
}

// ---------------- Phase 2: sequential recurrence ----------------
// grid 256 (one WG per batch row) x 512 threads (8 waves, ~1 WG/CU).
// Thread t: gate outputs o0=t, o1=t+512 with o = gate*256 + h  =>
//   sel = t>>8: sel0 -> (f[h], g[h]), sel1 -> (i[h], o[h]), h = t&255.
// Sh: p = t>>2, chunk c = t&3 covers 64 hidden dims; quad shfl reduce.
__global__ __launch_bounds__(512, 2) void rec_kernel(
    const _Float16* __restrict__ sx, const float* __restrict__ proto,
    const float* __restrict__ Wf, const float* __restrict__ bfv,
    const float* __restrict__ Wi, const float* __restrict__ biv,
    const float* __restrict__ Wg, const float* __restrict__ bgv,
    const float* __restrict__ Wo, const float* __restrict__ bov,
    float* __restrict__ out) {
  const int b = blockIdx.x;
  const int t = threadIdx.x;
  const int h = t & (HH - 1);
  const int sel = t >> 8;

  const float* W0 = sel ? Wi : Wf;
  const float* W1 = sel ? Wo : Wg;
  const float bias0 = sel ? biv[h] : bfv[h];
  const float bias1 = sel ? bov[h] : bgv[h];

  // fp16 gate weights in registers: 2 rows x 128 halves = 64+64 VGPRs
  h2 w0[PP / 2], w1[PP / 2];
#pragma unroll
  for (int j = 0; j < PP / 2; ++j) {
    float2 a = *(const float2*)(W0 + h * PP + 2 * j);
    float2 c = *(const float2*)(W1 + h * PP + 2 * j);
    h2 u; u.x = (_Float16)a.x; u.y = (_Float16)a.y; w0[j] = u;
    h2 v; v.x = (_Float16)c.x; v.y = (_Float16)c.y; w1[j] = v;
  }

  // hidden-part prototype slice, pre-scaled by -2 so Sh = hnorm + dot + pnorm
  const int p = t >> 2;
  const int cc = t & 3;
  h2 ph[32];
  float pnorm = 0.f;
#pragma unroll
  for (int j = 0; j < 32; ++j) {
    float2 a = *(const float2*)(proto + p * DHH + DD + cc * 64 + 2 * j);
    pnorm = fmaf(a.x, a.x, pnorm);
    pnorm = fmaf(a.y, a.y, pnorm);
    h2 u; u.x = (_Float16)(-2.f * a.x); u.y = (_Float16)(-2.f * a.y); ph[j] = u;
  }
  pnorm += __shfl_xor(pnorm, 1);
  pnorm += __shfl_xor(pnorm, 2);

  __shared__ __align__(16) h2 hx2[HH / 2];   // hx as fp16 pairs
  __shared__ __align__(16) h2 kh2[PP / 2];   // k as fp16 pairs
  __shared__ float fg[HH], ig[HH], gg[HH], og[HH];
  __shared__ float wpart[4];                 // per-wave ||hx||^2 partials

  if (t < HH / 2) { h2 z; z.x = (_Float16)0.f; z.y = (_Float16)0.f; hx2[t] = z; }
  if (t < 4) wpart[t] = 0.f;
  float cx = 0.f;
  float hxr = 0.f;
  __syncthreads();

  float sx_next = (float)sx[(size_t)b * PP + p];  // prefetch step 0

  for (int step = 0; step < TT; ++step) {
    // ---- Sh + k ----
    const float hnorm = wpart[0] + wpart[1] + wpart[2] + wpart[3];
    float dot = 0.f;
    const h2* hxc = hx2 + cc * 32;
#pragma unroll
    for (int j = 0; j < 32; ++j) dot = fdot2f(hxc[j], ph[j], dot);
    dot += __shfl_xor(dot, 1);
    dot += __shfl_xor(dot, 2);
    const float sx_cur = sx_next;
    const int nst = (step + 1 < TT) ? (step + 1) : (TT - 1);
    sx_next = (float)sx[((size_t)nst * BB + b) * PP + p];  // prefetch next step
    const float d2 = hnorm + dot + pnorm + sx_cur;
    const float kk = __expf(-d2);
    if (cc == 0) ((_Float16*)kh2)[p] = (_Float16)kk;
    __syncthreads();  // k ready

    // ---- gates: 2 outputs per thread, 64 fdot2 each ----
    float a0 = bias0, a1 = bias1;
#pragma unroll
    for (int j = 0; j < PP / 2; ++j) {
      const h2 kv = kh2[j];  // broadcast read
      a0 = fdot2f(kv, w0[j], a0);
      a1 = fdot2f(kv, w1[j], a1);
    }
    const float v0 = sigm_f(a0);
    const float v1 = sel ? sigm_f(a1) : tanh_f(a1);
    if (sel == 0) { fg[h] = v0; gg[h] = v1; }
    else          { ig[h] = v0; og[h] = v1; }
    __syncthreads();  // gates ready

    // ---- cell update (first 4 waves) ----
    if (t < HH) {
      const float f_ = fg[h], i_ = ig[h], g_ = gg[h], o_ = og[h];
      cx = fmaf(f_, cx, i_ * g_);
      hxr = o_ * tanh_f(cx);
      out[((size_t)step * BB + b) * HH + h] = hxr;
      ((_Float16*)hx2)[h] = (_Float16)hxr;
      float sq = hxr * hxr;
      sq += __shfl_xor(sq, 1);
      sq += __shfl_xor(sq, 2);
      sq += __shfl_xor(sq, 4);
      sq += __shfl_xor(sq, 8);
      sq += __shfl_xor(sq, 16);
      sq += __shfl_xor(sq, 32);
      if ((t & 63) == 0) wpart[t >> 6] = sq;
    }
    __syncthreads();  // hx2/wpart ready for next step
  }

  if (t < HH) {
    const size_t base = (size_t)TT * BB * HH;
    out[base + (size_t)b * HH + h] = hxr;                      // final hx
    out[base + (size_t)BB * HH + (size_t)b * HH + h] = cx;     // final cx
  }
}

extern "C" void kernel_launch(void* const* d_in, const int* in_sizes, int n_in,
                              void* d_out, int out_size, void* d_ws, size_t ws_size,
                              hipStream_t stream) {
  const float* x     = (const float*)d_in[0];
  const float* proto = (const float*)d_in[1];
  const float* Wf = (const float*)d_in[2];
  const float* bf = (const float*)d_in[3];
  const float* Wi = (const float*)d_in[4];
  const float* bi = (const float*)d_in[5];
  const float* Wg = (const float*)d_in[6];
  const float* bg = (const float*)d_in[7];
  const float* Wo = (const float*)d_in[8];
  const float* bo = (const float*)d_in[9];
  float* out = (float*)d_out;
  _Float16* sxbuf = (_Float16*)d_ws;  // needs T*B*P*2 = 32 MB scratch

  sx_kernel<<<1024, 256, 0, stream>>>(x, proto, sxbuf);
  rec_kernel<<<BB, 512, 0, stream>>>(sxbuf, proto, Wf, bf, Wi, bi, Wg, bg, Wo, bo, out);
}

// Round 3
// 995.452 us; speedup vs baseline: 1.4203x; 1.4203x over previous
//
#include <hip/hip_runtime.h>
#include <hip/hip_bf16.h>

// QLSTM: T=512, B=256, D=128, H=256, P=128, GAMMA=1
// Phase 1 (MFMA GEMM): sx[r,p] = ||x_r||^2 + ||px_p||^2 - 2 x_r.px_p  (full Sx, f16, 32MB ws)
// Phase 2 (sequential, 1 WG of 512 per batch row): Sh via padded-LDS fdot2,
//   k=exp(-(Sx+Sh)); gates via fp16 weights in VGPRs + b128 LDS broadcast of k.

#define TT 512
#define BB 256
#define DD 128
#define HH 256
#define PP 128
#define DHH 384

typedef _Float16 h2 __attribute__((ext_vector_type(2)));
typedef _Float16 h8 __attribute__((ext_vector_type(8)));
typedef float f4v __attribute__((ext_vector_type(4)));

union F4H { float4 f; h2 h[4]; };

__device__ __forceinline__ float fdot2f(h2 a, h2 b, float c) {
#if __has_builtin(__builtin_amdgcn_fdot2)
  return __builtin_amdgcn_fdot2(a, b, c, false);
#else
  return c + (float)a.x * (float)b.x + (float)a.y * (float)b.y;
#endif
}

__device__ __forceinline__ float sigm_f(float x) { return 1.f / (1.f + __expf(-x)); }
__device__ __forceinline__ float tanh_f(float x) { return 1.f - 2.f / (1.f + __expf(2.f * x)); }

// ---------------- Phase 1: Sx via MFMA f16 ----------------
// 512 WGs x 256 threads; each WG does 256 rows (4 tiles of 64), all 128 p.
// LDS rows padded to 136 halves (272B) to spread banks.
__global__ __launch_bounds__(256, 2) void sx_kernel(const float* __restrict__ x,
                                                    const float* __restrict__ proto,
                                                    _Float16* __restrict__ sx) {
  __shared__ __align__(16) _Float16 qlds[PP * 136];   // -2*proto_x, f16
  __shared__ __align__(16) _Float16 xlds[64 * 136];   // x tile, f16
  __shared__ float pnlds[PP];
  __shared__ float xnlds[64];

  const int t = threadIdx.x;
  const int lane = t & 63;
  const int wv = t >> 6;          // wave 0..3 -> m-tile
  const int col = lane & 15;
  const int quad = lane >> 4;
  const int r0 = blockIdx.x * 256;

  // ---- stage q = -2*proto_x (f16) + pnorm ----
  {
    const int p = t >> 1;
    const int hh = t & 1;
    const float* src = proto + p * DHH + hh * 64;
    _Float16* dst = qlds + p * 136 + hh * 64;
    float pn = 0.f;
#pragma unroll
    for (int i = 0; i < 8; ++i) {
      float4 a = *(const float4*)(src + i * 8);
      float4 b = *(const float4*)(src + i * 8 + 4);
      pn = fmaf(a.x, a.x, fmaf(a.y, a.y, fmaf(a.z, a.z, fmaf(a.w, a.w, pn))));
      pn = fmaf(b.x, b.x, fmaf(b.y, b.y, fmaf(b.z, b.z, fmaf(b.w, b.w, pn))));
      h8 v;
      v[0] = (_Float16)(-2.f * a.x); v[1] = (_Float16)(-2.f * a.y);
      v[2] = (_Float16)(-2.f * a.z); v[3] = (_Float16)(-2.f * a.w);
      v[4] = (_Float16)(-2.f * b.x); v[5] = (_Float16)(-2.f * b.y);
      v[6] = (_Float16)(-2.f * b.z); v[7] = (_Float16)(-2.f * b.w);
      *(h8*)(dst + i * 8) = v;
    }
    pn += __shfl_xor(pn, 1);
    if (hh == 0) pnlds[p] = pn;
  }

  // ---- stage x tile 0 ----
  {
    const int m = t >> 2;
    const int q4 = t & 3;
    const float* xs = x + ((size_t)(r0 + m)) * DD + q4 * 32;
    _Float16* xd = xlds + m * 136 + q4 * 32;
    float xn = 0.f;
#pragma unroll
    for (int i = 0; i < 4; ++i) {
      float4 a = *(const float4*)(xs + i * 8);
      float4 b = *(const float4*)(xs + i * 8 + 4);
      xn = fmaf(a.x, a.x, fmaf(a.y, a.y, fmaf(a.z, a.z, fmaf(a.w, a.w, xn))));
      xn = fmaf(b.x, b.x, fmaf(b.y, b.y, fmaf(b.z, b.z, fmaf(b.w, b.w, xn))));
      h8 v;
      v[0] = (_Float16)a.x; v[1] = (_Float16)a.y; v[2] = (_Float16)a.z; v[3] = (_Float16)a.w;
      v[4] = (_Float16)b.x; v[5] = (_Float16)b.y; v[6] = (_Float16)b.z; v[7] = (_Float16)b.w;
      *(h8*)(xd + i * 8) = v;
    }
    xn += __shfl_xor(xn, 1);
    xn += __shfl_xor(xn, 2);
    if (q4 == 0) xnlds[m] = xn;
  }
  __syncthreads();

  float pn8[8];
#pragma unroll
  for (int nt = 0; nt < 8; ++nt) pn8[nt] = pnlds[nt * 16 + col];

  for (int tile = 0; tile < 4; ++tile) {
    // ---- compute: wave wv owns 16 rows m0 = wv*16 of this tile ----
    h8 af[4];
#pragma unroll
    for (int kc = 0; kc < 4; ++kc)
      af[kc] = *(const h8*)(xlds + (wv * 16 + col) * 136 + kc * 32 + quad * 8);
    float xnq[4];
#pragma unroll
    for (int r = 0; r < 4; ++r) xnq[r] = xnlds[wv * 16 + quad * 4 + r];

#pragma unroll
    for (int nt = 0; nt < 8; ++nt) {
      f4v acc;
      acc[0] = pn8[nt]; acc[1] = pn8[nt]; acc[2] = pn8[nt]; acc[3] = pn8[nt];
#pragma unroll
      for (int kc = 0; kc < 4; ++kc) {
        h8 bf = *(const h8*)(qlds + (nt * 16 + col) * 136 + kc * 32 + quad * 8);
        acc = __builtin_amdgcn_mfma_f32_16x16x32_f16(af[kc], bf, acc, 0, 0, 0);
      }
#pragma unroll
      for (int r = 0; r < 4; ++r) {
        const int row = r0 + tile * 64 + wv * 16 + quad * 4 + r;
        sx[(size_t)row * PP + nt * 16 + col] = (_Float16)(acc[r] + xnq[r]);
      }
    }

    // ---- stage next x tile ----
    if (tile < 3) {
      __syncthreads();  // compute done before xlds overwrite
      const int m = t >> 2;
      const int q4 = t & 3;
      const float* xs = x + ((size_t)(r0 + (tile + 1) * 64 + m)) * DD + q4 * 32;
      _Float16* xd = xlds + m * 136 + q4 * 32;
      float xn = 0.f;
#pragma unroll
      for (int i = 0; i < 4; ++i) {
        float4 a = *(const float4*)(xs + i * 8);
        float4 b = *(const float4*)(xs + i * 8 + 4);
        xn = fmaf(a.x, a.x, fmaf(a.y, a.y, fmaf(a.z, a.z, fmaf(a.w, a.w, xn))));
        xn = fmaf(b.x, b.x, fmaf(b.y, b.y, fmaf(b.z, b.z, fmaf(b.w, b.w, xn))));
        h8 v;
        v[0] = (_Float16)a.x; v[1] = (_Float16)a.y; v[2] = (_Float16)a.z; v[3] = (_Float16)a.w;
        v[4] = (_Float16)b.x; v[5] = (_Float16)b.y; v[6] = (_Float16)b.z; v[7] = (_Float16)b.w;
        *(h8*)(xd + i * 8) = v;
      }
      xn += __shfl_xor(xn, 1);
      xn += __shfl_xor(xn, 2);
      if (q4 == 0) xnlds[m] = xn;
      __syncthreads();
    }
  }
}

// ---------------- Phase 2: sequential recurrence ----------------
// grid 256 x 512 threads. Thread t: gate rows (sel? i,o : f,g) for h=t&255.
// hx in LDS as 4 chunks of 32 h2 padded to stride 36 (bank-conflict-free b128).
__global__ __launch_bounds__(512, 2) void rec_kernel(
    const _Float16* __restrict__ sx, const float* __restrict__ proto,
    const float* __restrict__ Wf, const float* __restrict__ bfv,
    const float* __restrict__ Wi, const float* __restrict__ biv,
    const float* __restrict__ Wg, const float* __restrict__ bgv,
    const float* __restrict__ Wo, const float* __restrict__ bov,
    float* __restrict__ out) {
  const int b = blockIdx.x;
  const int t = threadIdx.x;
  const int h = t & (HH - 1);
  const int sel = t >> 8;

  const float* W0 = sel ? Wi : Wf;
  const float* W1 = sel ? Wo : Wg;
  const float bias0 = sel ? biv[h] : bfv[h];
  const float bias1 = sel ? bov[h] : bgv[h];

  h2 w0[PP / 2], w1[PP / 2];
#pragma unroll
  for (int j = 0; j < PP / 2; ++j) {
    float2 a = *(const float2*)(W0 + h * PP + 2 * j);
    float2 c = *(const float2*)(W1 + h * PP + 2 * j);
    h2 u; u.x = (_Float16)a.x; u.y = (_Float16)a.y; w0[j] = u;
    h2 v; v.x = (_Float16)c.x; v.y = (_Float16)c.y; w1[j] = v;
  }

  const int p = t >> 2;
  const int cc = t & 3;
  h2 ph[32];
  float pnorm = 0.f;
#pragma unroll
  for (int j = 0; j < 32; ++j) {
    float2 a = *(const float2*)(proto + p * DHH + DD + cc * 64 + 2 * j);
    pnorm = fmaf(a.x, a.x, pnorm);
    pnorm = fmaf(a.y, a.y, pnorm);
    h2 u; u.x = (_Float16)(-2.f * a.x); u.y = (_Float16)(-2.f * a.y); ph[j] = u;
  }
  pnorm += __shfl_xor(pnorm, 1);
  pnorm += __shfl_xor(pnorm, 2);

  // hx chunks: chunk c holds dims [c*64, c*64+64) at halves [c*72, c*72+64)
  __shared__ __align__(16) _Float16 hx2[4 * 72];
  __shared__ __align__(16) _Float16 kh2[PP];
  __shared__ float fg[HH], ig[HH], gg[HH], og[HH];
  __shared__ float wpart[4];

  if (t < HH) hx2[(h >> 6) * 72 + (h & 63)] = (_Float16)0.f;
  if (t < 4) wpart[t] = 0.f;
  float cx = 0.f;
  float hxr = 0.f;
  __syncthreads();

  float sx_next = (float)sx[(size_t)b * PP + p];

  for (int step = 0; step < TT; ++step) {
    // ---- Sh + k ----
    const float hnorm = wpart[0] + wpart[1] + wpart[2] + wpart[3];
    const _Float16* hxc = hx2 + cc * 72;
    float dotA = 0.f, dotB = 0.f;
#pragma unroll
    for (int j4 = 0; j4 < 8; ++j4) {
      F4H u; u.f = *(const float4*)(hxc + j4 * 8);
      dotA = fdot2f(u.h[0], ph[4 * j4 + 0], dotA);
      dotB = fdot2f(u.h[1], ph[4 * j4 + 1], dotB);
      dotA = fdot2f(u.h[2], ph[4 * j4 + 2], dotA);
      dotB = fdot2f(u.h[3], ph[4 * j4 + 3], dotB);
    }
    float dot = dotA + dotB;
    dot += __shfl_xor(dot, 1);
    dot += __shfl_xor(dot, 2);
    const float sx_cur = sx_next;
    const int nst = (step + 1 < TT) ? (step + 1) : (TT - 1);
    sx_next = (float)sx[((size_t)nst * BB + b) * PP + p];
    const float d2 = hnorm + dot + pnorm + sx_cur;
    const float kk = __expf(-d2);
    if (cc == 0) kh2[p] = (_Float16)kk;
    __syncthreads();  // k ready

    // ---- gates: 2 outputs/thread, b128 k broadcast, 4 acc chains ----
    float a0 = bias0, a1 = bias1, b0 = 0.f, b1 = 0.f;
#pragma unroll
    for (int j4 = 0; j4 < 16; ++j4) {
      F4H u; u.f = *(const float4*)(kh2 + j4 * 8);
      a0 = fdot2f(u.h[0], w0[4 * j4 + 0], a0);
      b0 = fdot2f(u.h[1], w0[4 * j4 + 1], b0);
      a0 = fdot2f(u.h[2], w0[4 * j4 + 2], a0);
      b0 = fdot2f(u.h[3], w0[4 * j4 + 3], b0);
      a1 = fdot2f(u.h[0], w1[4 * j4 + 0], a1);
      b1 = fdot2f(u.h[1], w1[4 * j4 + 1], b1);
      a1 = fdot2f(u.h[2], w1[4 * j4 + 2], a1);
      b1 = fdot2f(u.h[3], w1[4 * j4 + 3], b1);
    }
    a0 += b0; a1 += b1;
    const float v0 = sigm_f(a0);
    const float v1 = sel ? sigm_f(a1) : tanh_f(a1);
    if (sel == 0) { fg[h] = v0; gg[h] = v1; }
    else          { ig[h] = v0; og[h] = v1; }
    __syncthreads();  // gates ready

    // ---- cell update (first 4 waves) ----
    if (t < HH) {
      const float f_ = fg[h], i_ = ig[h], g_ = gg[h], o_ = og[h];
      cx = fmaf(f_, cx, i_ * g_);
      hxr = o_ * tanh_f(cx);
      out[((size_t)step * BB + b) * HH + h] = hxr;
      hx2[(h >> 6) * 72 + (h & 63)] = (_Float16)hxr;
      float sq = hxr * hxr;
      sq += __shfl_xor(sq, 1);
      sq += __shfl_xor(sq, 2);
      sq += __shfl_xor(sq, 4);
      sq += __shfl_xor(sq, 8);
      sq += __shfl_xor(sq, 16);
      sq += __shfl_xor(sq, 32);
      if ((t & 63) == 0) wpart[t >> 6] = sq;
    }
    __syncthreads();  // hx2/wpart ready for next step
  }

  if (t < HH) {
    const size_t base = (size_t)TT * BB * HH;
    out[base + (size_t)b * HH + h] = hxr;
    out[base + (size_t)BB * HH + (size_t)b * HH + h] = cx;
  }
}

extern "C" void kernel_launch(void* const* d_in, const int* in_sizes, int n_in,
                              void* d_out, int out_size, void* d_ws, size_t ws_size,
                              hipStream_t stream) {
  const float* x     = (const float*)d_in[0];
  const float* proto = (const float*)d_in[1];
  const float* Wf = (const float*)d_in[2];
  const float* bf = (const float*)d_in[3];
  const float* Wi = (const float*)d_in[4];
  const float* bi = (const float*)d_in[5];
  const float* Wg = (const float*)d_in[6];
  const float* bg = (const float*)d_in[7];
  const float* Wo = (const float*)d_in[8];
  const float* bo = (const float*)d_in[9];
  float* out = (float*)d_out;
  _Float16* sxbuf = (_Float16*)d_ws;  // T*B*P*2 = 32 MB

  sx_kernel<<<512, 256, 0, stream>>>(x, proto, sxbuf);
  rec_kernel<<<BB, 512, 0, stream>>>(sxbuf, proto, Wf, bf, Wi, bi, Wg, bg, Wo, bo, out);
}